// Round 1
// baseline (361.998 us; speedup 1.0000x reference)
//
#include <hip/hip_runtime.h>
#include <hip/hip_bf16.h>
#include <math.h>

#define AS1 __attribute__((address_space(1)))
#define AS3 __attribute__((address_space(3)))

typedef _Float16 f16x8 __attribute__((ext_vector_type(8)));
typedef float f32x4 __attribute__((ext_vector_type(4)));

#define NROWS 8192
#define DDIM  512

// ---------------------------------------------------------------------------
// Kernel 1: per-row prep. One wave (64 lanes) per row; each lane owns 8 cols.
//  - xh[i,k] = f16(x[i,k])
//  - ah[i,k] = f16(x[i,k] * rho[k])
//  - mu_out[i] = sum_k x*muk + mu_bias   (fp32, wave-reduced)
//  - dvec[i]   = softplus(sum_k x*vark + var_bias) + 1e-8
// ---------------------------------------------------------------------------
__global__ __launch_bounds__(256) void prep_kernel(
    const float* __restrict__ x,
    const float* __restrict__ muk,
    const float* __restrict__ rho,
    const float* __restrict__ vark,
    const float* __restrict__ mu_bias,
    const float* __restrict__ var_bias,
    float* __restrict__ mu_out,
    _Float16* __restrict__ xh,
    _Float16* __restrict__ ah,
    float* __restrict__ dvec)
{
    const int wave = threadIdx.x >> 6;
    const int lane = threadIdx.x & 63;
    const int row  = blockIdx.x * 4 + wave;
    const int k    = lane * 8;

    const float4 x0 = *(const float4*)(x + (size_t)row * DDIM + k);
    const float4 x1 = *(const float4*)(x + (size_t)row * DDIM + k + 4);
    const float4 m0 = *(const float4*)(muk + k);
    const float4 m1 = *(const float4*)(muk + k + 4);
    const float4 r0 = *(const float4*)(rho + k);
    const float4 r1 = *(const float4*)(rho + k + 4);
    const float4 v0 = *(const float4*)(vark + k);
    const float4 v1 = *(const float4*)(vark + k + 4);

    float xv[8] = {x0.x, x0.y, x0.z, x0.w, x1.x, x1.y, x1.z, x1.w};
    float rv[8] = {r0.x, r0.y, r0.z, r0.w, r1.x, r1.y, r1.z, r1.w};
    float mv[8] = {m0.x, m0.y, m0.z, m0.w, m1.x, m1.y, m1.z, m1.w};
    float vv[8] = {v0.x, v0.y, v0.z, v0.w, v1.x, v1.y, v1.z, v1.w};

    f16x8 hx, ha;
    float dm = 0.f, dv = 0.f;
#pragma unroll
    for (int j = 0; j < 8; ++j) {
        hx[j] = (_Float16)xv[j];
        ha[j] = (_Float16)(xv[j] * rv[j]);
        dm += xv[j] * mv[j];
        dv += xv[j] * vv[j];
    }
    *(f16x8*)(xh + (size_t)row * DDIM + k) = hx;
    *(f16x8*)(ah + (size_t)row * DDIM + k) = ha;

#pragma unroll
    for (int off = 32; off > 0; off >>= 1) {
        dm += __shfl_down(dm, off, 64);
        dv += __shfl_down(dv, off, 64);
    }
    if (lane == 0) {
        mu_out[row] = dm + mu_bias[0];
        float z  = dv + var_bias[0];
        float sp = fmaxf(z, 0.f) + log1pf(expf(-fabsf(z)));  // stable softplus
        dvec[row] = sp + 1e-8f;
    }
}

// ---------------------------------------------------------------------------
// Kernel 2: C[i,j] = sum_k ah[i,k]*xh[j,k] + cov_bias ; C[i,i] = dvec[i].
// m97 structure: 128x128 tile, BK=32, 256 thr (4 waves, 2x2), 16x16x32 f16
// MFMA, global_load_lds width=16 into unpadded row-major LDS tiles.
// ---------------------------------------------------------------------------
__device__ __forceinline__ void gload_lds16(const void* g, void* l)
{
    __builtin_amdgcn_global_load_lds((AS1 void*)g, (AS3 void*)l, 16, 0, 0);
}

__global__ __launch_bounds__(256) void cov_kernel(
    const _Float16* __restrict__ A,   // ah: 8192 x 512 (rows of x*rho)
    const _Float16* __restrict__ B,   // xh: 8192 x 512 (rows of x)
    const float* __restrict__ dvec,
    const float* __restrict__ cov_bias,
    float* __restrict__ C)
{
    __shared__ _Float16 As[128 * 32];   // 8 KB, row-major, 32-elem rows
    __shared__ _Float16 Bs[128 * 32];

    const int t    = threadIdx.x;
    const int lane = t & 63;
    const int wave = t >> 6;
    const int wr   = wave >> 1;         // 0..1 : 64-row half
    const int wc   = wave & 1;          // 0..1 : 64-col half
    const int quad = lane >> 4;         // 0..3
    const int l16  = lane & 15;

    const int rowBase = blockIdx.y * 128;
    const int colBase = blockIdx.x * 128;
    const float cb = cov_bias[0];

    f32x4 acc[4][4] = {};

    // staging addresses: thread t loads 16 B (8 halves): row t>>2, chunk t&3
    const _Float16* ga = A + ((size_t)(rowBase + (t >> 2))) * DDIM + (t & 3) * 8;
    const _Float16* gb = B + ((size_t)(colBase + (t >> 2))) * DDIM + (t & 3) * 8;

#pragma unroll 1
    for (int kt = 0; kt < 16; ++kt) {
        const int k0 = kt * 32;
        gload_lds16(ga + k0,             As + t * 8);
        gload_lds16(ga + 64 * DDIM + k0, As + 2048 + t * 8);
        gload_lds16(gb + k0,             Bs + t * 8);
        gload_lds16(gb + 64 * DDIM + k0, Bs + 2048 + t * 8);
        __syncthreads();

        f16x8 af[4], bf[4];
#pragma unroll
        for (int i = 0; i < 4; ++i)
            af[i] = *(const f16x8*)(As + (wr * 64 + i * 16 + l16) * 32 + quad * 8);
#pragma unroll
        for (int j = 0; j < 4; ++j)
            bf[j] = *(const f16x8*)(Bs + (wc * 64 + j * 16 + l16) * 32 + quad * 8);

#pragma unroll
        for (int i = 0; i < 4; ++i)
#pragma unroll
            for (int j = 0; j < 4; ++j)
                acc[i][j] = __builtin_amdgcn_mfma_f32_16x16x32_f16(af[i], bf[j], acc[i][j], 0, 0, 0);
        __syncthreads();
    }

    // epilogue: C/D layout col=lane&15, row=quad*4+reg
#pragma unroll
    for (int i = 0; i < 4; ++i) {
        const int grb = rowBase + wr * 64 + i * 16 + quad * 4;
#pragma unroll
        for (int j = 0; j < 4; ++j) {
            const int gc = colBase + wc * 64 + j * 16 + l16;
#pragma unroll
            for (int r = 0; r < 4; ++r) {
                const int gr = grb + r;
                float v = acc[i][j][r] + cb;
                if (gr == gc) v = dvec[gr];
                C[(size_t)gr * NROWS + gc] = v;
            }
        }
    }
}

// ---------------------------------------------------------------------------
extern "C" void kernel_launch(void* const* d_in, const int* in_sizes, int n_in,
                              void* d_out, int out_size, void* d_ws, size_t ws_size,
                              hipStream_t stream)
{
    const float* x     = (const float*)d_in[0];
    const float* muk   = (const float*)d_in[1];
    const float* rho   = (const float*)d_in[2];
    const float* vark  = (const float*)d_in[3];
    const float* mu_b  = (const float*)d_in[4];
    const float* var_b = (const float*)d_in[5];
    const float* cov_b = (const float*)d_in[6];

    float* out = (float*)d_out;                  // [0,8192): mu ; then cov row-major

    _Float16* xh = (_Float16*)d_ws;              // 8 MB
    _Float16* ah = xh + (size_t)NROWS * DDIM;    // 8 MB
    float* dvec  = (float*)(ah + (size_t)NROWS * DDIM);  // 32 KB

    prep_kernel<<<NROWS / 4, 256, 0, stream>>>(x, muk, rho, vark, mu_b, var_b,
                                               out, xh, ah, dvec);
    cov_kernel<<<dim3(NROWS / 128, NROWS / 128), 256, 0, stream>>>(
        ah, xh, dvec, cov_b, out + NROWS);
}

// Round 2
// 359.957 us; speedup vs baseline: 1.0057x; 1.0057x over previous
//
#include <hip/hip_runtime.h>
#include <hip/hip_bf16.h>
#include <math.h>

#define AS1 __attribute__((address_space(1)))
#define AS3 __attribute__((address_space(3)))

typedef _Float16 f16x8 __attribute__((ext_vector_type(8)));
typedef float f32x4 __attribute__((ext_vector_type(4)));

#define NROWS 8192
#define DDIM  512

// ---------------------------------------------------------------------------
// Kernel 1: per-row prep. One wave (64 lanes) per row; each lane owns 8 cols.
//  - xh[i,k] = f16(x[i,k])
//  - ah[i,k] = f16(x[i,k] * rho[k])
//  - mu_out[i] = sum_k x*muk + mu_bias   (fp32, wave-reduced)
//  - dvec[i]   = softplus(sum_k x*vark + var_bias) + 1e-8
// ---------------------------------------------------------------------------
__global__ __launch_bounds__(256) void prep_kernel(
    const float* __restrict__ x,
    const float* __restrict__ muk,
    const float* __restrict__ rho,
    const float* __restrict__ vark,
    const float* __restrict__ mu_bias,
    const float* __restrict__ var_bias,
    float* __restrict__ mu_out,
    _Float16* __restrict__ xh,
    _Float16* __restrict__ ah,
    float* __restrict__ dvec)
{
    const int wave = threadIdx.x >> 6;
    const int lane = threadIdx.x & 63;
    const int row  = blockIdx.x * 4 + wave;
    const int k    = lane * 8;

    const float4 x0 = *(const float4*)(x + (size_t)row * DDIM + k);
    const float4 x1 = *(const float4*)(x + (size_t)row * DDIM + k + 4);
    const float4 m0 = *(const float4*)(muk + k);
    const float4 m1 = *(const float4*)(muk + k + 4);
    const float4 r0 = *(const float4*)(rho + k);
    const float4 r1 = *(const float4*)(rho + k + 4);
    const float4 v0 = *(const float4*)(vark + k);
    const float4 v1 = *(const float4*)(vark + k + 4);

    float xv[8] = {x0.x, x0.y, x0.z, x0.w, x1.x, x1.y, x1.z, x1.w};
    float rv[8] = {r0.x, r0.y, r0.z, r0.w, r1.x, r1.y, r1.z, r1.w};
    float mv[8] = {m0.x, m0.y, m0.z, m0.w, m1.x, m1.y, m1.z, m1.w};
    float vv[8] = {v0.x, v0.y, v0.z, v0.w, v1.x, v1.y, v1.z, v1.w};

    f16x8 hx, ha;
    float dm = 0.f, dv = 0.f;
#pragma unroll
    for (int j = 0; j < 8; ++j) {
        hx[j] = (_Float16)xv[j];
        ha[j] = (_Float16)(xv[j] * rv[j]);
        dm += xv[j] * mv[j];
        dv += xv[j] * vv[j];
    }
    *(f16x8*)(xh + (size_t)row * DDIM + k) = hx;
    *(f16x8*)(ah + (size_t)row * DDIM + k) = ha;

#pragma unroll
    for (int off = 32; off > 0; off >>= 1) {
        dm += __shfl_down(dm, off, 64);
        dv += __shfl_down(dv, off, 64);
    }
    if (lane == 0) {
        mu_out[row] = dm + mu_bias[0];
        float z  = dv + var_bias[0];
        float sp = fmaxf(z, 0.f) + log1pf(expf(-fabsf(z)));  // stable softplus
        dvec[row] = sp + 1e-8f;
    }
}

// ---------------------------------------------------------------------------
// Kernel 2: C[i,j] = sum_k ah[i,k]*xh[j,k] + cov_bias ; C[i,i] = dvec[i].
// cov is SYMMETRIC => compute only lower-triangular 128x128 blocks (bj<=bi),
// write each off-diagonal block twice (normal + transposed orientation).
// Transposed write needs no LDS: acc[i][j][0..3] are 4 consecutive rows of
// the same col => one float4 in the transposed tile; the 4 quads of a given
// l16 form a contiguous 64B segment.
// m97 structure: 128x128 tile, BK=32, 256 thr (4 waves, 2x2), 16x16x32 f16
// MFMA, global_load_lds width=16 into unpadded row-major LDS tiles.
// ---------------------------------------------------------------------------
__device__ __forceinline__ void gload_lds16(const void* g, void* l)
{
    __builtin_amdgcn_global_load_lds((AS1 void*)g, (AS3 void*)l, 16, 0, 0);
}

__global__ __launch_bounds__(256) void cov_kernel(
    const _Float16* __restrict__ A,   // ah: 8192 x 512 (rows of x*rho)
    const _Float16* __restrict__ B,   // xh: 8192 x 512 (rows of x)
    const float* __restrict__ dvec,
    const float* __restrict__ cov_bias,
    float* __restrict__ C)
{
    __shared__ _Float16 As[128 * 32];   // 8 KB, row-major, 32-elem rows
    __shared__ _Float16 Bs[128 * 32];

    const int t    = threadIdx.x;
    const int lane = t & 63;
    const int wave = t >> 6;
    const int wr   = wave >> 1;         // 0..1 : 64-row half
    const int wc   = wave & 1;          // 0..1 : 64-col half
    const int quad = lane >> 4;         // 0..3
    const int l16  = lane & 15;

    // triangular decode: blockIdx.x -> (bi, bj), bj <= bi
    const int tt = blockIdx.x;
    int bi = (int)((sqrtf(8.f * (float)tt + 1.f) - 1.f) * 0.5f);
    while ((bi + 1) * (bi + 2) / 2 <= tt) ++bi;   // fixup fp rounding
    while (bi * (bi + 1) / 2 > tt) --bi;
    const int bj = tt - bi * (bi + 1) / 2;

    const int rowBase = bi * 128;
    const int colBase = bj * 128;
    const float cb = cov_bias[0];

    f32x4 acc[4][4] = {};

    // staging addresses: thread t loads 16 B (8 halves): row t>>2, chunk t&3
    const _Float16* ga = A + ((size_t)(rowBase + (t >> 2))) * DDIM + (t & 3) * 8;
    const _Float16* gb = B + ((size_t)(colBase + (t >> 2))) * DDIM + (t & 3) * 8;

#pragma unroll 1
    for (int kt = 0; kt < 16; ++kt) {
        const int k0 = kt * 32;
        gload_lds16(ga + k0,             As + t * 8);
        gload_lds16(ga + 64 * DDIM + k0, As + 2048 + t * 8);
        gload_lds16(gb + k0,             Bs + t * 8);
        gload_lds16(gb + 64 * DDIM + k0, Bs + 2048 + t * 8);
        __syncthreads();

        f16x8 af[4], bf[4];
#pragma unroll
        for (int i = 0; i < 4; ++i)
            af[i] = *(const f16x8*)(As + (wr * 64 + i * 16 + l16) * 32 + quad * 8);
#pragma unroll
        for (int j = 0; j < 4; ++j)
            bf[j] = *(const f16x8*)(Bs + (wc * 64 + j * 16 + l16) * 32 + quad * 8);

#pragma unroll
        for (int i = 0; i < 4; ++i)
#pragma unroll
            for (int j = 0; j < 4; ++j)
                acc[i][j] = __builtin_amdgcn_mfma_f32_16x16x32_f16(af[i], bf[j], acc[i][j], 0, 0, 0);
        __syncthreads();
    }

    // epilogue 1: normal orientation. C/D layout col=lane&15, row=quad*4+reg
#pragma unroll
    for (int i = 0; i < 4; ++i) {
        const int grb = rowBase + wr * 64 + i * 16 + quad * 4;
#pragma unroll
        for (int j = 0; j < 4; ++j) {
            const int gc = colBase + wc * 64 + j * 16 + l16;
#pragma unroll
            for (int r = 0; r < 4; ++r) {
                const int gr = grb + r;
                float v = acc[i][j][r] + cb;
                if (gr == gc) v = dvec[gr];   // only possible when bi==bj
                C[(size_t)gr * NROWS + gc] = v;
            }
        }
    }

    // epilogue 2: transposed orientation (off-diagonal blocks only).
    // T[row=gc][col=gr..gr+3] = acc[i][j][0..3]  -> one float4 store.
    if (bi != bj) {
#pragma unroll
        for (int j = 0; j < 4; ++j) {
            const int trow = colBase + wc * 64 + j * 16 + l16;   // row in C
#pragma unroll
            for (int i = 0; i < 4; ++i) {
                const int tcol = rowBase + wr * 64 + i * 16 + quad * 4;
                float4 v;
                v.x = acc[i][j][0] + cb;
                v.y = acc[i][j][1] + cb;
                v.z = acc[i][j][2] + cb;
                v.w = acc[i][j][3] + cb;
                *(float4*)(C + (size_t)trow * NROWS + tcol) = v;
            }
        }
    }
}

// ---------------------------------------------------------------------------
extern "C" void kernel_launch(void* const* d_in, const int* in_sizes, int n_in,
                              void* d_out, int out_size, void* d_ws, size_t ws_size,
                              hipStream_t stream)
{
    const float* x     = (const float*)d_in[0];
    const float* muk   = (const float*)d_in[1];
    const float* rho   = (const float*)d_in[2];
    const float* vark  = (const float*)d_in[3];
    const float* mu_b  = (const float*)d_in[4];
    const float* var_b = (const float*)d_in[5];
    const float* cov_b = (const float*)d_in[6];

    float* out = (float*)d_out;                  // [0,8192): mu ; then cov row-major

    _Float16* xh = (_Float16*)d_ws;              // 8 MB
    _Float16* ah = xh + (size_t)NROWS * DDIM;    // 8 MB
    float* dvec  = (float*)(ah + (size_t)NROWS * DDIM);  // 32 KB

    prep_kernel<<<NROWS / 4, 256, 0, stream>>>(x, muk, rho, vark, mu_b, var_b,
                                               out, xh, ah, dvec);

    const int nblk = (NROWS / 128) * (NROWS / 128 + 1) / 2;   // 64*65/2 = 2080
    cov_kernel<<<nblk, 256, 0, stream>>>(ah, xh, dvec, cov_b, out + NROWS);
}